// Round 1
// 63.896 us; speedup vs baseline: 1.0300x; 1.0300x over previous
//
#include <hip/hip_runtime.h>

#define NQ 8
#define NL 4
#define BATCH 4096

// ---------------------------------------------------------------------------
// Layout: one wave = ONE sample (was 4/wave). 256 amps = 64 lanes x 4 regs:
//   amp index a = (lane << 2) | r.  Wire i <-> amp bit (7 - i):
//   wires 0..5 <-> lane bits 5..0 (cross-lane), wires 6..7 <-> reg bits 1..0.
// 4096 waves -> 4 waves/SIMD (vs 1 before): the old kernel ran at effective
// CPI ~9 (26us vs 5.7us issue-bound) because 1024 waves on 1024 SIMDs left
// zero TLP to hide DPP/swizzle/trans latency. This layout trades slightly
// more cross-lane traffic for 4x latency hiding.
//
// CNOT ring fused into ONE wave-wide permutation: the 8 sequential CNOTs
// compose to  B_k' = parity(B_k..B7) (k<7), B7' = parity(B0..B6).
// Inverse:    B_k = B_k'^B_{k+1}' (k<6), B6 = B6'^B0'^B7', B7 = B0'^B7'.
// => source lane = (lane ^ (lane>>1)) ^ (r'&1 ? 0x30 : 0)   (gray code!)
//    source reg slot prep = 2-way permute selected by popc(lane)&1.
// Ring cost: 8 cndmask + 8 ds_bpermute (was ~240 instructions).
//
// Last layer pruned: after the final ring only RY(wire0) can change <Z_0>
// (RZ are diagonal; RY on wires>=1 preserve per-bit7-half norms). Exact.
// ---------------------------------------------------------------------------

template <int CTRL>
__device__ __forceinline__ float dppx(float v) {
  return __int_as_float(
      __builtin_amdgcn_update_dpp(0, __float_as_int(v), CTRL, 0xF, 0xF, true));
}

__device__ __forceinline__ float swz16(float v) {  // lane ^ 16 (within 32)
  return __int_as_float(__builtin_amdgcn_ds_swizzle(__float_as_int(v), 0x401F));
}
__device__ __forceinline__ float swz4(float v) {   // lane ^ 4
  return __int_as_float(__builtin_amdgcn_ds_swizzle(__float_as_int(v), 0x101F));
}
__device__ __forceinline__ float bperm(int addr, float v) {  // full-wave pull
  return __int_as_float(__builtin_amdgcn_ds_bpermute(addr, __float_as_int(v)));
}

// lane exchange along wire W (0..5): partner differs in lane bit (5-W)
template <int W>
__device__ __forceinline__ float xl(float v, int bp32) {
  if constexpr (W == 0) return bperm(bp32, v);       // lane ^ 32
  else if constexpr (W == 1) return swz16(v);        // lane ^ 16
  else if constexpr (W == 2) return dppx<0x128>(v);  // row_ror:8 == lane ^ 8
  else if constexpr (W == 3) return swz4(v);         // lane ^ 4
  else if constexpr (W == 4) return dppx<0x4E>(v);   // quad_perm [2,3,0,1] == ^2
  else return dppx<0xB1>(v);                         // quad_perm [1,0,3,2] == ^1
}

template <int W>
__device__ __forceinline__ void ry_gate(float re[4], float im[4],
                                        float c, float s, int lane, int bp32) {
  if constexpr (W <= 5) {
    const float ss = ((lane >> (5 - W)) & 1) ? s : -s;
#pragma unroll
    for (int r = 0; r < 4; ++r) {
      float pr = xl<W>(re[r], bp32);
      float pi = xl<W>(im[r], bp32);
      re[r] = c * re[r] + ss * pr;
      im[r] = c * im[r] + ss * pi;
    }
  } else {
    constexpr int m = 1 << (7 - W);  // W=6 -> reg bit1, W=7 -> reg bit0
#pragma unroll
    for (int r = 0; r < 4; ++r) {
      if ((r & m) == 0) {
        const int r1 = r | m;
        float a0r = re[r], a1r = re[r1];
        float a0i = im[r], a1i = im[r1];
        re[r]  = c * a0r - s * a1r;
        re[r1] = s * a0r + c * a1r;
        im[r]  = c * a0i - s * a1i;
        im[r1] = s * a0i + c * a1i;
      }
    }
  }
}

template <int W>
__device__ __forceinline__ void rz_gate(float re[4], float im[4],
                                        float c, float s, int lane) {
  if constexpr (W <= 5) {
    const float ss = ((lane >> (5 - W)) & 1) ? s : -s;
#pragma unroll
    for (int r = 0; r < 4; ++r) {
      float nr = re[r] * c - im[r] * ss;
      float ni = im[r] * c + re[r] * ss;
      re[r] = nr; im[r] = ni;
    }
  } else {
    constexpr int m = 1 << (7 - W);
#pragma unroll
    for (int r = 0; r < 4; ++r) {
      const float ss = (r & m) ? s : -s;  // compile-time sign per register
      float nr = re[r] * c - im[r] * ss;
      float ni = im[r] * c + re[r] * ss;
      re[r] = nr; im[r] = ni;
    }
  }
}

// Entire CNOT ring as one permutation gather.
// Slot prep (source side): dest reg r' = j gets source reg
//   reg[((j>>1)^P2)<<1 | ((j&1)^(j>>1))],  P2 = popc(lane)&1:
//   P2=0 -> (r0,r1,r3,r2) ; P2=1 -> (r2,r3,r1,r0)
// Gather addr: even r' -> gray(lane)<<2 ; odd r' -> ^0xC0 (flip lane bits 5,4)
__device__ __forceinline__ void ring(float re[4], float im[4],
                                     int addr_e, int addr_o, bool p2) {
  const float t0r = p2 ? re[2] : re[0];
  const float t1r = p2 ? re[3] : re[1];
  const float t2r = p2 ? re[1] : re[3];
  const float t3r = p2 ? re[0] : re[2];
  const float t0i = p2 ? im[2] : im[0];
  const float t1i = p2 ? im[3] : im[1];
  const float t2i = p2 ? im[1] : im[3];
  const float t3i = p2 ? im[0] : im[2];
  re[0] = bperm(addr_e, t0r);
  re[1] = bperm(addr_o, t1r);
  re[2] = bperm(addr_e, t2r);
  re[3] = bperm(addr_o, t3r);
  im[0] = bperm(addr_e, t0i);
  im[1] = bperm(addr_o, t1i);
  im[2] = bperm(addr_e, t2i);
  im[3] = bperm(addr_o, t3i);
}

__global__ __launch_bounds__(256, 4) void vqc_kernel(const float* __restrict__ x,
                                                     const float* __restrict__ w,
                                                     float* __restrict__ out) {
  const int lane = (int)(threadIdx.x & 63);
  const int s = (int)((blockIdx.x * blockDim.x + threadIdx.x) >> 6);  // wave id

  // hoisted cross-lane addresses
  const int gray   = lane ^ (lane >> 1);
  const int addr_e = gray << 2;          // ring gather, even dest regs
  const int addr_o = addr_e ^ 0xC0;      // ring gather, odd dest regs
  const bool p2    = (__popc(lane) & 1) != 0;
  const int bp32   = (lane ^ 32) << 2;   // wire-0 partner

  float re[4] = {0.f, 0.f, 0.f, 0.f};
  float im[4] = {0.f, 0.f, 0.f, 0.f};
  if (lane == 0) re[0] = 1.f;  // |0...0>

  // Angle encoding: RY(x_i) on wire i
  {
    const float4 x0 = *(const float4*)&x[s * 8];
    const float4 x1 = *(const float4*)&x[s * 8 + 4];
    float c, sn;
    __sincosf(x0.x * 0.5f, &sn, &c); ry_gate<0>(re, im, c, sn, lane, bp32);
    __sincosf(x0.y * 0.5f, &sn, &c); ry_gate<1>(re, im, c, sn, lane, bp32);
    __sincosf(x0.z * 0.5f, &sn, &c); ry_gate<2>(re, im, c, sn, lane, bp32);
    __sincosf(x0.w * 0.5f, &sn, &c); ry_gate<3>(re, im, c, sn, lane, bp32);
    __sincosf(x1.x * 0.5f, &sn, &c); ry_gate<4>(re, im, c, sn, lane, bp32);
    __sincosf(x1.y * 0.5f, &sn, &c); ry_gate<5>(re, im, c, sn, lane, bp32);
    __sincosf(x1.z * 0.5f, &sn, &c); ry_gate<6>(re, im, c, sn, lane, bp32);
    __sincosf(x1.w * 0.5f, &sn, &c); ry_gate<7>(re, im, c, sn, lane, bp32);
  }

  // Layers 0..NL-2: full ring + rotations
#pragma unroll
  for (int l = 0; l < NL - 1; ++l) {
    ring(re, im, addr_e, addr_o, p2);
    const float* wl = &w[l * NQ * 2];
#define APPLY_ROT(W) { float cy, sy, cz, sz;            \
    __sincosf(wl[(W) * 2 + 0] * 0.5f, &sy, &cy);        \
    __sincosf(wl[(W) * 2 + 1] * 0.5f, &sz, &cz);        \
    ry_gate<W>(re, im, cy, sy, lane, bp32);             \
    rz_gate<W>(re, im, cz, sz, lane); }
    APPLY_ROT(0) APPLY_ROT(1) APPLY_ROT(2) APPLY_ROT(3)
    APPLY_ROT(4) APPLY_ROT(5) APPLY_ROT(6) APPLY_ROT(7)
#undef APPLY_ROT
  }

  // Last layer: ring + RY(wire0) only — all other rotations provably
  // leave <Z_0> unchanged (diagonal, or unitary within fixed-bit7 halves).
  ring(re, im, addr_e, addr_o, p2);
  {
    float cy, sy;
    __sincosf(w[(NL - 1) * NQ * 2 + 0] * 0.5f, &sy, &cy);
    ry_gate<0>(re, im, cy, sy, lane, bp32);
  }

  // <Z_0>: wire 0 = amp bit 7 = lane bit 5; sign then full-wave reduction
  float acc = 0.f;
#pragma unroll
  for (int r = 0; r < 4; ++r) acc += re[r] * re[r] + im[r] * im[r];
  acc = (lane & 32) ? -acc : acc;
  acc += dppx<0xB1>(acc);   // ^1
  acc += dppx<0x4E>(acc);   // ^2
  acc += swz4(acc);         // ^4
  acc += dppx<0x128>(acc);  // ^8
  acc += swz16(acc);        // ^16
  acc += bperm(bp32, acc);  // ^32
  if (lane == 0) out[s] = acc;
}

extern "C" void kernel_launch(void* const* d_in, const int* in_sizes, int n_in,
                              void* d_out, int out_size, void* d_ws, size_t ws_size,
                              hipStream_t stream) {
  const float* x = (const float*)d_in[0];   // (4096, 8) f32
  const float* w = (const float*)d_in[1];   // (4, 8, 2) f32
  float* out = (float*)d_out;               // (4096,) f32
  (void)in_sizes; (void)n_in; (void)out_size; (void)d_ws; (void)ws_size;

  // 1 sample per wave: 4096 waves = 1024 blocks x 256 threads = 4 waves/SIMD
  dim3 grid(BATCH * 64 / 256), block(256);
  hipLaunchKernelGGL(vqc_kernel, grid, block, 0, stream, x, w, out);
}

// Round 2
// 63.010 us; speedup vs baseline: 1.0444x; 1.0141x over previous
//
#include <hip/hip_runtime.h>

#define NQ 8
#define NL 4
#define BATCH 4096

// ---------------------------------------------------------------------------
// Layout: one wave = one sample. 256 amps = 64 lanes x 4 regs:
//   amp index a = (lane << 2) | r.  Wire i <-> amp bit (7 - i):
//   wires 0..5 <-> lane bits 5..0 (cross-lane), wires 6..7 <-> reg bits 1..0.
//
// CNOT ring fused into ONE wave-wide permutation (gray-code gather):
//   forward (amp bits): A_j = parity(B_j..B7) (j<7), A_7 = parity(B0..B6)
//   inverse:            B_j = A_j^A_{j+1} (j<6), B6 = A7^A0^A6, B7 = A0^A7
//
// NEW this round — encoding + FIRST ring folded into a closed form:
// the encoded state is a real product state amp(b) = prod_i f_i(wirebit_i),
// f_i(0)=cos(x_i/2), f_i(1)=sin(x_i/2); permuting a product state by a
// bit-linear map gives another product-of-parities expression:
//   amp'(lane,r) = P_lane * f7(r0^r1) * f6(r1^L0) * f1(L4^L5^r0) * f0(L5^r0)
//   P_lane = f5(L0^L1) f4(L1^L2) f3(L2^L3) f2(L3^L4)
// ~40 VALU, zero DS, replaces 8 RY gates + 1 ring (~250 instr, 32 DS).
// State stays REAL until layer-0 RZ(0) -> RY(0)/RZ(0) specialized on re only.
//
// Last layer pruned: after the final ring only RY(wire0) can change <Z_0>.
// ---------------------------------------------------------------------------

template <int CTRL>
__device__ __forceinline__ float dppx(float v) {
  return __int_as_float(
      __builtin_amdgcn_update_dpp(0, __float_as_int(v), CTRL, 0xF, 0xF, true));
}

__device__ __forceinline__ float swz16(float v) {  // lane ^ 16
  return __int_as_float(__builtin_amdgcn_ds_swizzle(__float_as_int(v), 0x401F));
}
__device__ __forceinline__ float swz4(float v) {   // lane ^ 4
  return __int_as_float(__builtin_amdgcn_ds_swizzle(__float_as_int(v), 0x101F));
}
__device__ __forceinline__ float bperm(int addr, float v) {  // full-wave pull
  return __int_as_float(__builtin_amdgcn_ds_bpermute(addr, __float_as_int(v)));
}

// lane exchange along wire W (0..5): partner differs in lane bit (5-W)
template <int W>
__device__ __forceinline__ float xl(float v, int bp32) {
  if constexpr (W == 0) return bperm(bp32, v);       // lane ^ 32
  else if constexpr (W == 1) return swz16(v);        // lane ^ 16
  else if constexpr (W == 2) return dppx<0x128>(v);  // row_ror:8 == lane ^ 8
  else if constexpr (W == 3) return swz4(v);         // lane ^ 4
  else if constexpr (W == 4) return dppx<0x4E>(v);   // quad_perm [2,3,0,1] == ^2
  else return dppx<0xB1>(v);                         // quad_perm [1,0,3,2] == ^1
}

template <int W>
__device__ __forceinline__ void ry_gate(float re[4], float im[4],
                                        float c, float s, int lane, int bp32) {
  if constexpr (W <= 5) {
    const float ss = ((lane >> (5 - W)) & 1) ? s : -s;
#pragma unroll
    for (int r = 0; r < 4; ++r) {
      float pr = xl<W>(re[r], bp32);
      float pi = xl<W>(im[r], bp32);
      re[r] = c * re[r] + ss * pr;
      im[r] = c * im[r] + ss * pi;
    }
  } else {
    constexpr int m = 1 << (7 - W);  // W=6 -> reg bit1, W=7 -> reg bit0
#pragma unroll
    for (int r = 0; r < 4; ++r) {
      if ((r & m) == 0) {
        const int r1 = r | m;
        float a0r = re[r], a1r = re[r1];
        float a0i = im[r], a1i = im[r1];
        re[r]  = c * a0r - s * a1r;
        re[r1] = s * a0r + c * a1r;
        im[r]  = c * a0i - s * a1i;
        im[r1] = s * a0i + c * a1i;
      }
    }
  }
}

template <int W>
__device__ __forceinline__ void rz_gate(float re[4], float im[4],
                                        float c, float s, int lane) {
  if constexpr (W <= 5) {
    const float ss = ((lane >> (5 - W)) & 1) ? s : -s;
#pragma unroll
    for (int r = 0; r < 4; ++r) {
      float nr = re[r] * c - im[r] * ss;
      float ni = im[r] * c + re[r] * ss;
      re[r] = nr; im[r] = ni;
    }
  } else {
    constexpr int m = 1 << (7 - W);
#pragma unroll
    for (int r = 0; r < 4; ++r) {
      const float ss = (r & m) ? s : -s;  // compile-time sign per register
      float nr = re[r] * c - im[r] * ss;
      float ni = im[r] * c + re[r] * ss;
      re[r] = nr; im[r] = ni;
    }
  }
}

// Entire CNOT ring as one permutation gather.
// Slot prep: P2 = popc(lane)&1: P2=0 -> (r0,r1,r3,r2) ; P2=1 -> (r2,r3,r1,r0)
// Gather addr: even r' -> gray(lane)<<2 ; odd r' -> ^0xC0 (flip lane bits 5,4)
__device__ __forceinline__ void ring(float re[4], float im[4],
                                     int addr_e, int addr_o, bool p2) {
  const float t0r = p2 ? re[2] : re[0];
  const float t1r = p2 ? re[3] : re[1];
  const float t2r = p2 ? re[1] : re[3];
  const float t3r = p2 ? re[0] : re[2];
  const float t0i = p2 ? im[2] : im[0];
  const float t1i = p2 ? im[3] : im[1];
  const float t2i = p2 ? im[1] : im[3];
  const float t3i = p2 ? im[0] : im[2];
  re[0] = bperm(addr_e, t0r);
  re[1] = bperm(addr_o, t1r);
  re[2] = bperm(addr_e, t2r);
  re[3] = bperm(addr_o, t3r);
  im[0] = bperm(addr_e, t0i);
  im[1] = bperm(addr_o, t1i);
  im[2] = bperm(addr_e, t2i);
  im[3] = bperm(addr_o, t3i);
}

__global__ __launch_bounds__(256, 4) void vqc_kernel(const float* __restrict__ x,
                                                     const float* __restrict__ w,
                                                     float* __restrict__ out) {
  const int lane = (int)(threadIdx.x & 63);
  const int s = (int)((blockIdx.x * blockDim.x + threadIdx.x) >> 6);  // wave id

  // hoisted cross-lane addresses
  const int gray   = lane ^ (lane >> 1);   // bit k = L_k ^ L_{k+1}
  const int addr_e = gray << 2;            // ring gather, even dest regs
  const int addr_o = addr_e ^ 0xC0;        // ring gather, odd dest regs
  const bool p2    = (__popc(lane) & 1) != 0;
  const int bp32   = (lane ^ 32) << 2;     // wire-0 partner

  // ---- encoding angles
  float fc[8], fs[8];
  {
    const float4 x0 = *(const float4*)&x[s * 8];
    const float4 x1 = *(const float4*)&x[s * 8 + 4];
    __sincosf(x0.x * 0.5f, &fs[0], &fc[0]);
    __sincosf(x0.y * 0.5f, &fs[1], &fc[1]);
    __sincosf(x0.z * 0.5f, &fs[2], &fc[2]);
    __sincosf(x0.w * 0.5f, &fs[3], &fc[3]);
    __sincosf(x1.x * 0.5f, &fs[4], &fc[4]);
    __sincosf(x1.y * 0.5f, &fs[5], &fc[5]);
    __sincosf(x1.z * 0.5f, &fs[6], &fc[6]);
    __sincosf(x1.w * 0.5f, &fs[7], &fc[7]);
  }

  // ---- direct construction of the post-ring-0 state (REAL), zero DS ops.
  // dest amp bits: A7..A2 = lane bits 5..0, A1 = r bit1, A0 = r bit0.
  // source wire bits: w_i = B_{7-i};  B_j = A_j^A_{j+1} (j<6),
  //   B6 = A7^A0^A6 = L5^r0^L4,  B7 = A0^A7 = r0^L5.
  float re[4], im[4];
  {
    const int L0  = lane & 1;
    const int L5b = (lane >> 5) & 1;
    const float g2 = (gray & 1) ? fs[5] : fc[5];  // f5(L0^L1)
    const float g3 = (gray & 2) ? fs[4] : fc[4];  // f4(L1^L2)
    const float g4 = (gray & 4) ? fs[3] : fc[3];  // f3(L2^L3)
    const float g5 = (gray & 8) ? fs[2] : fc[2];  // f2(L3^L4)
    const float Pl = (g2 * g3) * (g4 * g5);
    const int  b6 = ((lane >> 4) & 1) ^ L5b;      // L4^L5
    const float h0 = (b6  ? fs[1] : fc[1]) * (L5b ? fs[0] : fc[0]);  // r0=0
    const float h1 = (b6  ? fc[1] : fs[1]) * (L5b ? fc[0] : fs[0]);  // r0=1
    const float A0 = Pl * h0, A1 = Pl * h1;
    const float f6a = L0 ? fs[6] : fc[6];         // f6(L0)    (r1=0)
    const float f6b = L0 ? fc[6] : fs[6];         // f6(1^L0)  (r1=1)
    re[0] = A0 * fc[7] * f6a;   // r=00: B0=0
    re[1] = A1 * fs[7] * f6a;   // r=01: B0=1
    re[2] = A0 * fs[7] * f6b;   // r=10: B0=1
    re[3] = A1 * fc[7] * f6b;   // r=11: B0=0
    im[0] = 0.f; im[1] = 0.f; im[2] = 0.f; im[3] = 0.f;
  }

#define APPLY_ROT(WL, W) { float cy, sy, cz, sz;         \
    __sincosf((WL)[(W) * 2 + 0] * 0.5f, &sy, &cy);       \
    __sincosf((WL)[(W) * 2 + 1] * 0.5f, &sz, &cz);       \
    ry_gate<W>(re, im, cy, sy, lane, bp32);              \
    rz_gate<W>(re, im, cz, sz, lane); }

  // ---- layer 0 (ring already folded). State is real through RY(0)/RZ(0).
  {
    const float* wl = &w[0];
    float cy, sy, cz, sz;
    __sincosf(wl[0] * 0.5f, &sy, &cy);
    __sincosf(wl[1] * 0.5f, &sz, &cz);
    const float ssy = (lane & 32) ? sy : -sy;
#pragma unroll
    for (int r = 0; r < 4; ++r) {   // RY(0) on real state: re half only
      float p = bperm(bp32, re[r]);
      re[r] = cy * re[r] + ssy * p;
    }
    const float ssz = (lane & 32) ? sz : -sz;
#pragma unroll
    for (int r = 0; r < 4; ++r) {   // RZ(0) on real state
      im[r] = ssz * re[r];
      re[r] = cz * re[r];
    }
    APPLY_ROT(wl, 1) APPLY_ROT(wl, 2) APPLY_ROT(wl, 3)
    APPLY_ROT(wl, 4) APPLY_ROT(wl, 5) APPLY_ROT(wl, 6) APPLY_ROT(wl, 7)
  }

  // ---- layers 1..NL-2: full ring + rotations
#pragma unroll
  for (int l = 1; l < NL - 1; ++l) {
    ring(re, im, addr_e, addr_o, p2);
    const float* wl = &w[l * NQ * 2];
    APPLY_ROT(wl, 0) APPLY_ROT(wl, 1) APPLY_ROT(wl, 2) APPLY_ROT(wl, 3)
    APPLY_ROT(wl, 4) APPLY_ROT(wl, 5) APPLY_ROT(wl, 6) APPLY_ROT(wl, 7)
  }
#undef APPLY_ROT

  // ---- last layer: ring + RY(wire0) only (rest provably drops out of <Z_0>)
  ring(re, im, addr_e, addr_o, p2);
  {
    float cy, sy;
    __sincosf(w[(NL - 1) * NQ * 2 + 0] * 0.5f, &sy, &cy);
    ry_gate<0>(re, im, cy, sy, lane, bp32);
  }

  // ---- <Z_0>: wire 0 = amp bit 7 = lane bit 5; sign then wave reduction
  float acc = 0.f;
#pragma unroll
  for (int r = 0; r < 4; ++r) acc += re[r] * re[r] + im[r] * im[r];
  acc = (lane & 32) ? -acc : acc;
  acc += dppx<0xB1>(acc);   // ^1
  acc += dppx<0x4E>(acc);   // ^2
  acc += swz4(acc);         // ^4
  acc += dppx<0x128>(acc);  // ^8
  acc += swz16(acc);        // ^16
  acc += bperm(bp32, acc);  // ^32
  if (lane == 0) out[s] = acc;
}

extern "C" void kernel_launch(void* const* d_in, const int* in_sizes, int n_in,
                              void* d_out, int out_size, void* d_ws, size_t ws_size,
                              hipStream_t stream) {
  const float* x = (const float*)d_in[0];   // (4096, 8) f32
  const float* w = (const float*)d_in[1];   // (4, 8, 2) f32
  float* out = (float*)d_out;               // (4096,) f32
  (void)in_sizes; (void)n_in; (void)out_size; (void)d_ws; (void)ws_size;

  // 1 sample per wave: 4096 waves = 1024 blocks x 256 threads = 4 waves/SIMD
  dim3 grid(BATCH * 64 / 256), block(256);
  hipLaunchKernelGGL(vqc_kernel, grid, block, 0, stream, x, w, out);
}

// Round 3
// 62.390 us; speedup vs baseline: 1.0548x; 1.0099x over previous
//
#include <hip/hip_runtime.h>

#define NQ 8
#define NL 4
#define BATCH 4096

// ---------------------------------------------------------------------------
// Layout: one wave = one sample. 256 amps = 64 lanes x 4 regs:
//   amp index a = (lane << 2) | r.  Wire i <-> amp bit (7 - i):
//   wires 0..5 <-> lane bits 5..0 (cross-lane), wires 6..7 <-> reg bits 1..0.
//
// CNOT ring = ONE wave-wide permutation (gray-code gather):
//   forward: A_j = parity(B_j..B7) (j<7), A_7 = parity(B0..B6)
//   inverse: B_j = A_j^A_{j+1} (j<6), B6 = A7^A0^A6, B7 = A0^A7
//
// Encoding + FIRST ring folded to a closed-form real product state (r2).
//
// NEW (r3):
//  * ALL rotation angles (64 weights + 8 x) get their sincos from ONE
//    lane-parallel __sincosf: lane i<56 -> w[i], lane 56+i -> x[s,i].
//    Scalars distributed by v_readlane (wave-uniform -> SGPR operands).
//    Replaces ~57 serial sincos/wave with 1 (+~114 readlane).
//  * LAST ring folded into readout: flipping post-ring A7 flips pre-ring
//    amp bits {6,7} only => final RY(0) pairs are (lane, lane^48) same reg;
//    Z-sign = parity(lane&31)^parity(reg). 4th ring's 8 bperm + prep gone.
//  * Per-gate sign selects -> precomputed sign-bit XOR masks.
// ---------------------------------------------------------------------------

template <int CTRL>
__device__ __forceinline__ float dppx(float v) {
  return __int_as_float(
      __builtin_amdgcn_update_dpp(0, __float_as_int(v), CTRL, 0xF, 0xF, true));
}

__device__ __forceinline__ float swz16(float v) {  // lane ^ 16
  return __int_as_float(__builtin_amdgcn_ds_swizzle(__float_as_int(v), 0x401F));
}
__device__ __forceinline__ float swz4(float v) {   // lane ^ 4
  return __int_as_float(__builtin_amdgcn_ds_swizzle(__float_as_int(v), 0x101F));
}
__device__ __forceinline__ float bperm(int addr, float v) {  // full-wave pull
  return __int_as_float(__builtin_amdgcn_ds_bpermute(addr, __float_as_int(v)));
}
__device__ __forceinline__ float rlane(float v, int l) {     // lane -> SGPR
  return __int_as_float(__builtin_amdgcn_readlane(__float_as_int(v), l));
}
__device__ __forceinline__ float sxor(float v, unsigned m) { // sign via xor
  return __int_as_float(__float_as_int(v) ^ m);
}

// lane exchange along wire W (0..5): partner differs in lane bit (5-W)
template <int W>
__device__ __forceinline__ float xl(float v, int bp32) {
  if constexpr (W == 0) return bperm(bp32, v);       // lane ^ 32
  else if constexpr (W == 1) return swz16(v);        // lane ^ 16
  else if constexpr (W == 2) return dppx<0x128>(v);  // row_ror:8 == lane ^ 8
  else if constexpr (W == 3) return swz4(v);         // lane ^ 4
  else if constexpr (W == 4) return dppx<0x4E>(v);   // quad_perm [2,3,0,1] == ^2
  else return dppx<0xB1>(v);                         // quad_perm [1,0,3,2] == ^1
}

// m: 0 where wire-bit==1 (ss=+s), 0x80000000 where wire-bit==0 (ss=-s)
template <int W>
__device__ __forceinline__ void ry_gate(float re[4], float im[4],
                                        float c, float s, unsigned m, int bp32) {
  if constexpr (W <= 5) {
    const float ss = sxor(s, m);
#pragma unroll
    for (int r = 0; r < 4; ++r) {
      float pr = xl<W>(re[r], bp32);
      float pi = xl<W>(im[r], bp32);
      re[r] = c * re[r] + ss * pr;
      im[r] = c * im[r] + ss * pi;
    }
  } else {
    constexpr int mm = 1 << (7 - W);  // W=6 -> reg bit1, W=7 -> reg bit0
#pragma unroll
    for (int r = 0; r < 4; ++r) {
      if ((r & mm) == 0) {
        const int r1 = r | mm;
        float a0r = re[r], a1r = re[r1];
        float a0i = im[r], a1i = im[r1];
        re[r]  = c * a0r - s * a1r;
        re[r1] = s * a0r + c * a1r;
        im[r]  = c * a0i - s * a1i;
        im[r1] = s * a0i + c * a1i;
      }
    }
  }
}

template <int W>
__device__ __forceinline__ void rz_gate(float re[4], float im[4],
                                        float c, float s, unsigned m) {
  if constexpr (W <= 5) {
    const float ss = sxor(s, m);
#pragma unroll
    for (int r = 0; r < 4; ++r) {
      float nr = re[r] * c - im[r] * ss;
      float ni = im[r] * c + re[r] * ss;
      re[r] = nr; im[r] = ni;
    }
  } else {
    constexpr int mm = 1 << (7 - W);
#pragma unroll
    for (int r = 0; r < 4; ++r) {
      const float ss = (r & mm) ? s : -s;  // compile-time sign per register
      float nr = re[r] * c - im[r] * ss;
      float ni = im[r] * c + re[r] * ss;
      re[r] = nr; im[r] = ni;
    }
  }
}

// Entire CNOT ring as one permutation gather.
// Slot prep: P2 = popc(lane)&1: P2=0 -> (r0,r1,r3,r2) ; P2=1 -> (r2,r3,r1,r0)
// Gather addr: even r' -> gray(lane)<<2 ; odd r' -> ^0xC0 (flip lane bits 5,4)
__device__ __forceinline__ void ring(float re[4], float im[4],
                                     int addr_e, int addr_o, bool p2) {
  const float t0r = p2 ? re[2] : re[0];
  const float t1r = p2 ? re[3] : re[1];
  const float t2r = p2 ? re[1] : re[3];
  const float t3r = p2 ? re[0] : re[2];
  const float t0i = p2 ? im[2] : im[0];
  const float t1i = p2 ? im[3] : im[1];
  const float t2i = p2 ? im[1] : im[3];
  const float t3i = p2 ? im[0] : im[2];
  re[0] = bperm(addr_e, t0r);
  re[1] = bperm(addr_o, t1r);
  re[2] = bperm(addr_e, t2r);
  re[3] = bperm(addr_o, t3r);
  im[0] = bperm(addr_e, t0i);
  im[1] = bperm(addr_o, t1i);
  im[2] = bperm(addr_e, t2i);
  im[3] = bperm(addr_o, t3i);
}

__global__ __launch_bounds__(256, 4) void vqc_kernel(const float* __restrict__ x,
                                                     const float* __restrict__ w,
                                                     float* __restrict__ out) {
  const int lane = (int)(threadIdx.x & 63);
  const int s = (int)((blockIdx.x * blockDim.x + threadIdx.x) >> 6);  // wave id

  // hoisted cross-lane addresses
  const int gray   = lane ^ (lane >> 1);   // bit k = L_k ^ L_{k+1}
  const int addr_e = gray << 2;            // ring gather, even dest regs
  const int addr_o = addr_e ^ 0xC0;        // ring gather, odd dest regs
  const bool p2    = (__popc(lane) & 1) != 0;
  const int bp32   = (lane ^ 32) << 2;     // wire-0 partner
  const int bp48   = (lane ^ 48) << 2;     // folded-last-ring partner

  // per-wire sign masks: ss = wirebit ? s : -s  ==  s ^ sm[W]
  unsigned sm[8];
#pragma unroll
  for (int W = 0; W < 6; ++W)
    sm[W] = ((lane >> (5 - W)) & 1) ? 0u : 0x80000000u;
  sm[6] = 0u; sm[7] = 0u;

  // ---- ONE sincos for all 64 weight angles + this sample's 8 x angles.
  // lane i<56: w[i] (only 0..48 consumed); lane 56+i: x[s,i].
  float sn, cs;
  {
    const float wv = w[lane];                       // w has exactly 64 floats
    const float xv = x[(s << 3) | (lane & 7)];
    const float ang = (lane >= 56) ? xv : wv;
    __sincosf(ang * 0.5f, &sn, &cs);
  }

  // ---- direct construction of the post-ring-0 state (REAL), zero DS ops.
  float re[4], im[4];
  {
    const float f0c = rlane(cs, 56), f0s = rlane(sn, 56);
    const float f1c = rlane(cs, 57), f1s = rlane(sn, 57);
    const float f2c = rlane(cs, 58), f2s = rlane(sn, 58);
    const float f3c = rlane(cs, 59), f3s = rlane(sn, 59);
    const float f4c = rlane(cs, 60), f4s = rlane(sn, 60);
    const float f5c = rlane(cs, 61), f5s = rlane(sn, 61);
    const float f6c = rlane(cs, 62), f6s = rlane(sn, 62);
    const float f7c = rlane(cs, 63), f7s = rlane(sn, 63);
    const int L0  = lane & 1;
    const int L5b = (lane >> 5) & 1;
    const float g2 = (gray & 1) ? f5s : f5c;  // f5(L0^L1)
    const float g3 = (gray & 2) ? f4s : f4c;  // f4(L1^L2)
    const float g4 = (gray & 4) ? f3s : f3c;  // f3(L2^L3)
    const float g5 = (gray & 8) ? f2s : f2c;  // f2(L3^L4)
    const float Pl = (g2 * g3) * (g4 * g5);
    const int  b6 = ((lane >> 4) & 1) ^ L5b;  // L4^L5
    const float h0 = (b6 ? f1s : f1c) * (L5b ? f0s : f0c);  // r0=0
    const float h1 = (b6 ? f1c : f1s) * (L5b ? f0c : f0s);  // r0=1
    const float A0 = Pl * h0, A1 = Pl * h1;
    const float f6a = L0 ? f6s : f6c;         // f6(L0)    (r1=0)
    const float f6b = L0 ? f6c : f6s;         // f6(1^L0)  (r1=1)
    re[0] = A0 * f7c * f6a;   // r=00: B0=0
    re[1] = A1 * f7s * f6a;   // r=01: B0=1
    re[2] = A0 * f7s * f6b;   // r=10: B0=1
    re[3] = A1 * f7c * f6b;   // r=11: B0=0
    im[0] = 0.f; im[1] = 0.f; im[2] = 0.f; im[3] = 0.f;
  }

#define APPLY_ROT(BASE, W) {                                 \
    const float cy = rlane(cs, (BASE) + (W) * 2);            \
    const float sy = rlane(sn, (BASE) + (W) * 2);            \
    const float cz = rlane(cs, (BASE) + (W) * 2 + 1);        \
    const float sz = rlane(sn, (BASE) + (W) * 2 + 1);        \
    ry_gate<W>(re, im, cy, sy, sm[W], bp32);                 \
    rz_gate<W>(re, im, cz, sz, sm[W]); }

  // ---- layer 0 (ring already folded). State real through RY(0)/RZ(0).
  {
    const float cy = rlane(cs, 0), sy = rlane(sn, 0);
    const float cz = rlane(cs, 1), sz = rlane(sn, 1);
    const float ssy = sxor(sy, sm[0]);
#pragma unroll
    for (int r = 0; r < 4; ++r) {   // RY(0) on real state: re half only
      float p = bperm(bp32, re[r]);
      re[r] = cy * re[r] + ssy * p;
    }
    const float ssz = sxor(sz, sm[0]);
#pragma unroll
    for (int r = 0; r < 4; ++r) {   // RZ(0) on real state
      im[r] = ssz * re[r];
      re[r] = cz * re[r];
    }
    APPLY_ROT(0, 1) APPLY_ROT(0, 2) APPLY_ROT(0, 3)
    APPLY_ROT(0, 4) APPLY_ROT(0, 5) APPLY_ROT(0, 6) APPLY_ROT(0, 7)
  }

  // ---- layers 1..NL-2: full ring + rotations
#pragma unroll
  for (int l = 1; l < NL - 1; ++l) {
    ring(re, im, addr_e, addr_o, p2);
    const int base = l * 16;
    APPLY_ROT(base, 0) APPLY_ROT(base, 1) APPLY_ROT(base, 2) APPLY_ROT(base, 3)
    APPLY_ROT(base, 4) APPLY_ROT(base, 5) APPLY_ROT(base, 6) APPLY_ROT(base, 7)
  }
#undef APPLY_ROT

  // ---- last layer, fully folded: ring_3 + RY(0) + <Z_0> in one pass.
  // Post-ring A7 flip <-> pre-ring amp bits {6,7} flip == lane ^ 48, same reg.
  // A7(slot) = parity(lane&31) ^ parity(reg) ; ss = A7 ? +s : -s ; Z-sign = -A7
  {
    const float cy = rlane(cs, (NL - 1) * 16);
    const float sy = rlane(sn, (NL - 1) * 16);
    const unsigned pm0 = (unsigned)(__popc(lane & 31) & 1) << 31;  // regs 0,3
    float acc = 0.f;
#pragma unroll
    for (int r = 0; r < 4; ++r) {
      const unsigned pmr = pm0 ^ (((r == 1) | (r == 2)) ? 0x80000000u : 0u);
      const float ssy = sxor(sy, pmr ^ 0x80000000u);
      const float pr = bperm(bp48, re[r]);
      const float pi = bperm(bp48, im[r]);
      const float nr = cy * re[r] + ssy * pr;
      const float ni = cy * im[r] + ssy * pi;
      const float m2 = nr * nr + ni * ni;
      acc += sxor(m2, pmr);            // + when A7=0, - when A7=1
    }
    // full-wave sum
    acc += dppx<0xB1>(acc);   // ^1
    acc += dppx<0x4E>(acc);   // ^2
    acc += swz4(acc);         // ^4
    acc += dppx<0x128>(acc);  // ^8
    acc += swz16(acc);        // ^16
    acc += bperm(bp32, acc);  // ^32
    if (lane == 0) out[s] = acc;
  }
}

extern "C" void kernel_launch(void* const* d_in, const int* in_sizes, int n_in,
                              void* d_out, int out_size, void* d_ws, size_t ws_size,
                              hipStream_t stream) {
  const float* x = (const float*)d_in[0];   // (4096, 8) f32
  const float* w = (const float*)d_in[1];   // (4, 8, 2) f32
  float* out = (float*)d_out;               // (4096,) f32
  (void)in_sizes; (void)n_in; (void)out_size; (void)d_ws; (void)ws_size;

  // 1 sample per wave: 4096 waves = 1024 blocks x 256 threads = 4 waves/SIMD
  dim3 grid(BATCH * 64 / 256), block(256);
  hipLaunchKernelGGL(vqc_kernel, grid, block, 0, stream, x, w, out);
}

// Round 4
// 61.611 us; speedup vs baseline: 1.0682x; 1.0126x over previous
//
#include <hip/hip_runtime.h>

#define NQ 8
#define NL 4
#define BATCH 4096

// ---------------------------------------------------------------------------
// Layout (r4): one wave = TWO samples. Sample = lane bit 5 (two 32-lane
// halves). Per sample: 256 amps = 32 lanes x 8 regs:
//   amp bits A7..A3 = hl bits 4..0 (hl = lane&31), A2..A0 = reg bits 2..0.
//   wire i <-> A_{7-i}:  wires 0-4 cross-lane (xor 16,8,4,2,1),
//                        wires 5-7 in-register (reg xor 4,2,1).
// Rationale: per-wave fixed overhead (~250 instr: readlanes, sincos, setup)
// now amortizes over 2 samples; wire0 bperm -> swizzle, wire1 -> DPP,
// wire5 -> in-reg. Total issued instr: 4096x~1300 -> 2048x~2070 (-22%).
// Trade: 2 waves/SIMD (was 4) -> less TLP for DS latency hiding.
//
// CNOT ring (per half): forward A_j = parity(B_j..B7) (j<7), A7=parity(B0..B6)
// inverse: B_j = A_j^A_{j+1} (j<=5), B6 = A7^A0^A6, B7 = A7^A0.
//   src lane  = (lane&32) | gray5(hl)   (odd dest regs: ^0x18)
//   src reg for dest reg j = gray3(j) ^ (parity(hl) ? 4 : 0)
// Verified on probe basis states (0->0; wire0; wire7; wire4).
//
// Encoding + ring0 folded to closed-form REAL product state (re-derived):
//   amp(hl,r) = f2(g2) f3(g1) f4(g0) * q_{r0} * g5_{r2} * f6(r2^r1) f7(r1^r0)
//   q0 = f0(HL4) f1(g3), q1 = f0(~HL4) f1(~g3); g5_b = f5(HL0^b); g=gray5(hl)
// Last ring + RY(w[48]) + <Z_0> folded into readout: partner = lane^0x18,
//   sign parity = parity(lane&15) ^ par3(reg).
// ---------------------------------------------------------------------------

template <int CTRL>
__device__ __forceinline__ float dppx(float v) {
  return __int_as_float(
      __builtin_amdgcn_update_dpp(0, __float_as_int(v), CTRL, 0xF, 0xF, true));
}

__device__ __forceinline__ float swz16(float v) {  // lane ^ 16
  return __int_as_float(__builtin_amdgcn_ds_swizzle(__float_as_int(v), 0x401F));
}
__device__ __forceinline__ float swz4(float v) {   // lane ^ 4
  return __int_as_float(__builtin_amdgcn_ds_swizzle(__float_as_int(v), 0x101F));
}
__device__ __forceinline__ float swz18(float v) {  // lane ^ 0x18
  return __int_as_float(__builtin_amdgcn_ds_swizzle(__float_as_int(v), 0x601F));
}
__device__ __forceinline__ float bperm(int addr, float v) {  // full-wave pull
  return __int_as_float(__builtin_amdgcn_ds_bpermute(addr, __float_as_int(v)));
}
__device__ __forceinline__ float rlane(float v, int l) {     // lane -> SGPR
  return __int_as_float(__builtin_amdgcn_readlane(__float_as_int(v), l));
}
__device__ __forceinline__ float sxor(float v, unsigned m) { // sign via xor
  return __int_as_float(__float_as_int(v) ^ m);
}

// lane exchange along wire W (0..4): partner differs in lane bit (4-W)
template <int W>
__device__ __forceinline__ float xl(float v) {
  if constexpr (W == 0) return swz16(v);             // lane ^ 16
  else if constexpr (W == 1) return dppx<0x128>(v);  // row_ror:8 == lane ^ 8
  else if constexpr (W == 2) return swz4(v);         // lane ^ 4
  else if constexpr (W == 3) return dppx<0x4E>(v);   // quad_perm [2,3,0,1] ^2
  else return dppx<0xB1>(v);                         // quad_perm [1,0,3,2] ^1
}

// m: 0 where wire-bit==1 (ss=+s), 0x80000000 where wire-bit==0 (ss=-s)
template <int W>
__device__ __forceinline__ void ry_gate(float re[8], float im[8],
                                        float c, float s, unsigned m) {
  if constexpr (W <= 4) {
    const float ss = sxor(s, m);
#pragma unroll
    for (int r = 0; r < 8; ++r) {
      float pr = xl<W>(re[r]);
      float pi = xl<W>(im[r]);
      re[r] = c * re[r] + ss * pr;
      im[r] = c * im[r] + ss * pi;
    }
  } else {
    constexpr int mm = 1 << (7 - W);  // W=5->4, 6->2, 7->1
#pragma unroll
    for (int r = 0; r < 8; ++r) {
      if ((r & mm) == 0) {
        const int r1 = r | mm;
        float a0r = re[r], a1r = re[r1];
        float a0i = im[r], a1i = im[r1];
        re[r]  = c * a0r - s * a1r;
        re[r1] = s * a0r + c * a1r;
        im[r]  = c * a0i - s * a1i;
        im[r1] = s * a0i + c * a1i;
      }
    }
  }
}

template <int W>
__device__ __forceinline__ void rz_gate(float re[8], float im[8],
                                        float c, float s, unsigned m) {
  if constexpr (W <= 4) {
    const float ss = sxor(s, m);
#pragma unroll
    for (int r = 0; r < 8; ++r) {
      float nr = re[r] * c - im[r] * ss;
      float ni = im[r] * c + re[r] * ss;
      re[r] = nr; im[r] = ni;
    }
  } else {
    constexpr int mm = 1 << (7 - W);
#pragma unroll
    for (int r = 0; r < 8; ++r) {
      const float ss = (r & mm) ? s : -s;  // compile-time sign per register
      float nr = re[r] * c - im[r] * ss;
      float ni = im[r] * c + re[r] * ss;
      re[r] = nr; im[r] = ni;
    }
  }
}

// Entire CNOT ring as one permutation gather (both samples at once).
// P = parity(hl). t_j = reg[gray3(j) ^ (P?4:0)]; even j -> addr_e, odd addr_o.
__device__ __forceinline__ void ring2(float re[8], float im[8],
                                      int addr_e, int addr_o, bool P) {
  const float t0r = P ? re[4] : re[0], t0i = P ? im[4] : im[0];
  const float t1r = P ? re[5] : re[1], t1i = P ? im[5] : im[1];
  const float t2r = P ? re[7] : re[3], t2i = P ? im[7] : im[3];
  const float t3r = P ? re[6] : re[2], t3i = P ? im[6] : im[2];
  const float t4r = P ? re[2] : re[6], t4i = P ? im[2] : im[6];
  const float t5r = P ? re[3] : re[7], t5i = P ? im[3] : im[7];
  const float t6r = P ? re[1] : re[5], t6i = P ? im[1] : im[5];
  const float t7r = P ? re[0] : re[4], t7i = P ? im[0] : im[4];
  re[0] = bperm(addr_e, t0r); re[1] = bperm(addr_o, t1r);
  re[2] = bperm(addr_e, t2r); re[3] = bperm(addr_o, t3r);
  re[4] = bperm(addr_e, t4r); re[5] = bperm(addr_o, t5r);
  re[6] = bperm(addr_e, t6r); re[7] = bperm(addr_o, t7r);
  im[0] = bperm(addr_e, t0i); im[1] = bperm(addr_o, t1i);
  im[2] = bperm(addr_e, t2i); im[3] = bperm(addr_o, t3i);
  im[4] = bperm(addr_e, t4i); im[5] = bperm(addr_o, t5i);
  im[6] = bperm(addr_e, t6i); im[7] = bperm(addr_o, t7i);
}

__global__ __launch_bounds__(256, 2) void vqc_kernel(const float* __restrict__ x,
                                                     const float* __restrict__ w,
                                                     float* __restrict__ out) {
  const int lane = (int)(threadIdx.x & 63);
  const int wv = (int)((blockIdx.x * blockDim.x + threadIdx.x) >> 6);
  const int hl = lane & 31;

  // ring gather addresses: src lane = (lane&32) | gray5(hl); odd regs ^0x18
  const int ghl    = hl ^ (hl >> 1);                 // 5-bit gray
  const int addr_e = ((lane & 32) | ghl) << 2;
  const int addr_o = addr_e ^ 0x60;                  // ^ (0x18 lanes) in bytes
  const bool Ppar  = (__popc(hl) & 1) != 0;

  // per-wire sign masks (wires 0..4 <-> lane bits 4..0)
  unsigned sm[8];
#pragma unroll
  for (int W = 0; W < 5; ++W)
    sm[W] = ((lane >> (4 - W)) & 1) ? 0u : 0x80000000u;
  sm[5] = 0u; sm[6] = 0u; sm[7] = 0u;

  // ---- ONE sincos: lanes 0..47 -> w[lane]; lanes 48..63 -> the wave's two
  // samples' x (16 floats, consecutive). w[48] (final RY0) done scalar.
  float sn, cs;
  {
    const float wvv = w[lane];
    const float xv  = x[(wv << 4) | (lane & 15)];
    const float ang = (lane >= 48) ? xv : wvv;
    __sincosf(ang * 0.5f, &sn, &cs);
  }
  float cy48, sy48;
  __sincosf(w[48] * 0.5f, &sy48, &cy48);

  // ---- distribute this HALF's encoding sincos values (per-sample)
  float fc[8], fs[8];
  {
    const int fbase = (48 + ((lane >> 5) << 3)) << 2;
#pragma unroll
    for (int k = 0; k < 8; ++k) {
      fc[k] = bperm(fbase + (k << 2), cs);
      fs[k] = bperm(fbase + (k << 2), sn);
    }
  }

  // ---- closed-form post-ring-0 REAL state
  float re[8], im[8];
  {
    const int HL4 = (lane >> 4) & 1, G3 = (ghl >> 3) & 1, HL0 = lane & 1;
    const float Pl = ((ghl & 4) ? fs[2] : fc[2]) *
                     ((ghl & 2) ? fs[3] : fc[3]) *
                     ((ghl & 1) ? fs[4] : fc[4]);
    const float q0 = (HL4 ? fs[0] : fc[0]) * (G3 ? fs[1] : fc[1]);
    const float q1 = (HL4 ? fc[0] : fs[0]) * (G3 ? fc[1] : fs[1]);
    const float g50 = HL0 ? fs[5] : fc[5];
    const float g51 = HL0 ? fc[5] : fs[5];
    const float a0 = Pl * q0 * g50, a1 = Pl * q1 * g50;
    const float b0 = Pl * q0 * g51, b1 = Pl * q1 * g51;
    const float cc = fc[6] * fc[7], csx = fc[6] * fs[7];
    const float sc = fs[6] * fc[7], ssx = fs[6] * fs[7];
    re[0] = a0 * cc;  re[1] = a1 * csx; re[2] = a0 * ssx; re[3] = a1 * sc;
    re[4] = b0 * sc;  re[5] = b1 * ssx; re[6] = b0 * csx; re[7] = b1 * cc;
#pragma unroll
    for (int r = 0; r < 8; ++r) im[r] = 0.f;
  }

#define APPLY_ROT(BASE, W) {                                 \
    const float cy = rlane(cs, (BASE) + (W) * 2);            \
    const float sy = rlane(sn, (BASE) + (W) * 2);            \
    const float cz = rlane(cs, (BASE) + (W) * 2 + 1);        \
    const float sz = rlane(sn, (BASE) + (W) * 2 + 1);        \
    ry_gate<W>(re, im, cy, sy, sm[W]);                       \
    rz_gate<W>(re, im, cz, sz, sm[W]); }

  // ---- layer 0 (ring folded). State real through RY(0)/RZ(0).
  {
    const float cy = rlane(cs, 0), sy = rlane(sn, 0);
    const float cz = rlane(cs, 1), sz = rlane(sn, 1);
    const float ssy = sxor(sy, sm[0]);
#pragma unroll
    for (int r = 0; r < 8; ++r) {   // RY(0) on real state: re half only
      float p = swz16(re[r]);
      re[r] = cy * re[r] + ssy * p;
    }
    const float ssz = sxor(sz, sm[0]);
#pragma unroll
    for (int r = 0; r < 8; ++r) {   // RZ(0) on real state
      im[r] = ssz * re[r];
      re[r] = cz * re[r];
    }
    APPLY_ROT(0, 1) APPLY_ROT(0, 2) APPLY_ROT(0, 3)
    APPLY_ROT(0, 4) APPLY_ROT(0, 5) APPLY_ROT(0, 6) APPLY_ROT(0, 7)
  }

  // ---- layers 1..2: full ring + rotations
#pragma unroll
  for (int l = 1; l < NL - 1; ++l) {
    ring2(re, im, addr_e, addr_o, Ppar);
    const int base = l * 16;
    APPLY_ROT(base, 0) APPLY_ROT(base, 1) APPLY_ROT(base, 2) APPLY_ROT(base, 3)
    APPLY_ROT(base, 4) APPLY_ROT(base, 5) APPLY_ROT(base, 6) APPLY_ROT(base, 7)
  }
#undef APPLY_ROT

  // ---- last layer folded: ring_3 + RY(w[48]) + <Z_0> in one pass.
  // Post-ring A7 flip <-> pre-ring hl bits {4,3} flip == lane^0x18, same reg.
  // A7 = parity(hl&0xF) ^ par3(reg); ss = A7 ? +s : -s; Z-sign = -A7.
  {
    const unsigned pm0 = (unsigned)(__popc(lane & 15) & 1) << 31;
    float acc = 0.f;
#pragma unroll
    for (int r = 0; r < 8; ++r) {
      const unsigned podd =
          ((r == 1) | (r == 2) | (r == 4) | (r == 7)) ? 0x80000000u : 0u;
      const unsigned pmr = pm0 ^ podd;
      const float ssy = sxor(sy48, pmr ^ 0x80000000u);
      const float pr = swz18(re[r]);
      const float pi = swz18(im[r]);
      const float nr = cy48 * re[r] + ssy * pr;
      const float ni = cy48 * im[r] + ssy * pi;
      acc += sxor(nr * nr + ni * ni, pmr);  // + when A7=0, - when A7=1
    }
    // reduce over the 32-lane half
    acc += dppx<0xB1>(acc);   // ^1
    acc += dppx<0x4E>(acc);   // ^2
    acc += swz4(acc);         // ^4
    acc += dppx<0x128>(acc);  // ^8
    acc += swz16(acc);        // ^16
    if ((lane & 31) == 0) out[(wv << 1) | (lane >> 5)] = acc;
  }
}

extern "C" void kernel_launch(void* const* d_in, const int* in_sizes, int n_in,
                              void* d_out, int out_size, void* d_ws, size_t ws_size,
                              hipStream_t stream) {
  const float* x = (const float*)d_in[0];   // (4096, 8) f32
  const float* w = (const float*)d_in[1];   // (4, 8, 2) f32
  float* out = (float*)d_out;               // (4096,) f32
  (void)in_sizes; (void)n_in; (void)out_size; (void)d_ws; (void)ws_size;

  // 2 samples per wave: 2048 waves = 512 blocks x 256 threads = 2 waves/SIMD
  dim3 grid(BATCH / 2 * 64 / 256), block(256);
  hipLaunchKernelGGL(vqc_kernel, grid, block, 0, stream, x, w, out);
}

// Round 5
// 60.106 us; speedup vs baseline: 1.0949x; 1.0250x over previous
//
#include <hip/hip_runtime.h>

#define NQ 8
#define NL 4
#define BATCH 4096

// ---------------------------------------------------------------------------
// Layout (r4): one wave = TWO samples. Sample = lane bit 5. Per sample:
// 256 amps = 32 lanes x 8 regs; amp bits A7..A3 = hl bits 4..0 (hl=lane&31),
// A2..A0 = reg bits 2..0. Wire i <-> A_{7-i}: wires 0-4 cross-lane
// (xor 16,8,4,2,1), wires 5-7 in-register (reg xor 4,2,1).
//
// r5 NEW — RZ-layer fusion + all-real layer 0 (both exact):
//  * In each layer, RZ(i) commutes with RY(j!=i) and all RZs -> layer ==
//    [RY(0..7)] then ONE diagonal D = prod_i RZ(i). D's phase is linear in
//    amp bits: phi = phi_lane (5 signed half-angles, one __sincosf/layer)
//    + phi_reg(r) (8 wave-uniform combos from (c5,s5)x(c6,s6)x(c7,s7),
//    conj symmetry r <-> 7-r). Apply once: 4 ops/amp. ~256 -> ~110 ALU/layer.
//  * Layer 0: RY matrices are real and the pre-layer state is real -> all 8
//    RYs run on re[] only (half cost); the fused diagonal then hits a real
//    state (re=C*t, im=S*t).
// Static count ~2070 -> ~1450 instr/wave.
//
// CNOT ring (per half): src lane = (lane&32)|gray5(hl) (odd dest regs ^0x18),
// src reg = gray3(j) ^ (parity(hl)?4:0). Encoding + ring0 folded to a
// closed-form real product state. Last ring + RY(w[48]) + <Z_0> folded into
// the readout: partner = lane^0x18, sign = parity(lane&15)^par3(reg).
// ---------------------------------------------------------------------------

template <int CTRL>
__device__ __forceinline__ float dppx(float v) {
  return __int_as_float(
      __builtin_amdgcn_update_dpp(0, __float_as_int(v), CTRL, 0xF, 0xF, true));
}

__device__ __forceinline__ float swz16(float v) {  // lane ^ 16
  return __int_as_float(__builtin_amdgcn_ds_swizzle(__float_as_int(v), 0x401F));
}
__device__ __forceinline__ float swz4(float v) {   // lane ^ 4
  return __int_as_float(__builtin_amdgcn_ds_swizzle(__float_as_int(v), 0x101F));
}
__device__ __forceinline__ float swz18(float v) {  // lane ^ 0x18
  return __int_as_float(__builtin_amdgcn_ds_swizzle(__float_as_int(v), 0x601F));
}
__device__ __forceinline__ float bperm(int addr, float v) {  // full-wave pull
  return __int_as_float(__builtin_amdgcn_ds_bpermute(addr, __float_as_int(v)));
}
__device__ __forceinline__ float rlane(float v, int l) {     // lane -> SGPR
  return __int_as_float(__builtin_amdgcn_readlane(__float_as_int(v), l));
}
__device__ __forceinline__ float sxor(float v, unsigned m) { // sign via xor
  return __int_as_float(__float_as_int(v) ^ m);
}

// lane exchange along wire W (0..4): partner differs in lane bit (4-W)
template <int W>
__device__ __forceinline__ float xl(float v) {
  if constexpr (W == 0) return swz16(v);             // lane ^ 16
  else if constexpr (W == 1) return dppx<0x128>(v);  // row_ror:8 == lane ^ 8
  else if constexpr (W == 2) return swz4(v);         // lane ^ 4
  else if constexpr (W == 3) return dppx<0x4E>(v);   // quad_perm [2,3,0,1] ^2
  else return dppx<0xB1>(v);                         // quad_perm [1,0,3,2] ^1
}

// m: 0 where wire-bit==1 (ss=+s), 0x80000000 where wire-bit==0 (ss=-s)
template <int W>
__device__ __forceinline__ void ry_gate(float re[8], float im[8],
                                        float c, float s, unsigned m) {
  if constexpr (W <= 4) {
    const float ss = sxor(s, m);
#pragma unroll
    for (int r = 0; r < 8; ++r) {
      float pr = xl<W>(re[r]);
      float pi = xl<W>(im[r]);
      re[r] = c * re[r] + ss * pr;
      im[r] = c * im[r] + ss * pi;
    }
  } else {
    constexpr int mm = 1 << (7 - W);
#pragma unroll
    for (int r = 0; r < 8; ++r) {
      if ((r & mm) == 0) {
        const int r1 = r | mm;
        float a0r = re[r], a1r = re[r1];
        float a0i = im[r], a1i = im[r1];
        re[r]  = c * a0r - s * a1r;
        re[r1] = s * a0r + c * a1r;
        im[r]  = c * a0i - s * a1i;
        im[r1] = s * a0i + c * a1i;
      }
    }
  }
}

// real-state RY (layer 0): acts on re[] only
template <int W>
__device__ __forceinline__ void ry_real(float re[8], float c, float s,
                                        unsigned m) {
  if constexpr (W <= 4) {
    const float ss = sxor(s, m);
#pragma unroll
    for (int r = 0; r < 8; ++r) {
      float pr = xl<W>(re[r]);
      re[r] = c * re[r] + ss * pr;
    }
  } else {
    constexpr int mm = 1 << (7 - W);
#pragma unroll
    for (int r = 0; r < 8; ++r) {
      if ((r & mm) == 0) {
        const int r1 = r | mm;
        float a0 = re[r], a1 = re[r1];
        re[r]  = c * a0 - s * a1;
        re[r1] = s * a0 + c * a1;
      }
    }
  }
}

// Fused RZ diagonal for one layer: amp *= exp(i*phi), phi = sum_i ±theta_i/2
// (+ where wire-bit==1). Wires 0-4 -> per-lane angle sum + one sincos;
// wires 5-7 -> 8 wave-uniform (cR,sR) with conj symmetry r <-> 7-r.
template <bool REAL>
__device__ __forceinline__ void rz_diag(float re[8], float im[8],
                                        float cs, float sn, float ha,
                                        const unsigned* sm, int base) {
  float phL = sxor(rlane(ha, base + 1), sm[0]);
  phL += sxor(rlane(ha, base + 3), sm[1]);
  phL += sxor(rlane(ha, base + 5), sm[2]);
  phL += sxor(rlane(ha, base + 7), sm[3]);
  phL += sxor(rlane(ha, base + 9), sm[4]);
  float sL, cL;
  __sincosf(phL, &sL, &cL);
  const float c5 = rlane(cs, base + 11), s5 = rlane(sn, base + 11);
  const float c6 = rlane(cs, base + 13), s6 = rlane(sn, base + 13);
  const float c7 = rlane(cs, base + 15), s7 = rlane(sn, base + 15);
  const float m1 = c5 * c6, m2 = s5 * s6, m3 = s5 * c6, m4 = c5 * s6;
  const float ppr = m1 - m2, ppi = m3 + m4;   // ph5+ * ph6+
  const float pmr = m1 + m2, pmi = m3 - m4;   // ph5+ * ph6-
  float cR[4], sR[4];                          // index k = r-4 for r=4..7
  {
    const float a = pmr * c7, b = pmi * s7, c2 = pmi * c7, d = pmr * s7;
    cR[0] = a + b; sR[0] = c2 - d;   // r=4: signs (+,-,-)
    cR[1] = a - b; sR[1] = c2 + d;   // r=5: signs (+,-,+)
  }
  {
    const float a = ppr * c7, b = ppi * s7, c2 = ppi * c7, d = ppr * s7;
    cR[2] = a + b; sR[2] = c2 - d;   // r=6: signs (+,+,-)
    cR[3] = a - b; sR[3] = c2 + d;   // r=7: signs (+,+,+)
  }
#pragma unroll
  for (int r = 0; r < 8; ++r) {
    const int k = (r < 4) ? (3 - r) : (r - 4);          // conj pair r ^ 7
    const float cRr = cR[k];
    const float sRr = (r < 4) ? -sR[k] : sR[k];
    const float C = cL * cRr - sL * sRr;
    const float S = sL * cRr + cL * sRr;
    if constexpr (REAL) {
      const float t = re[r];
      re[r] = C * t;
      im[r] = S * t;
    } else {
      const float tr = re[r], ti = im[r];
      re[r] = C * tr - S * ti;
      im[r] = C * ti + S * tr;
    }
  }
}

// Entire CNOT ring as one permutation gather (both samples at once).
__device__ __forceinline__ void ring2(float re[8], float im[8],
                                      int addr_e, int addr_o, bool P) {
  const float t0r = P ? re[4] : re[0], t0i = P ? im[4] : im[0];
  const float t1r = P ? re[5] : re[1], t1i = P ? im[5] : im[1];
  const float t2r = P ? re[7] : re[3], t2i = P ? im[7] : im[3];
  const float t3r = P ? re[6] : re[2], t3i = P ? im[6] : im[2];
  const float t4r = P ? re[2] : re[6], t4i = P ? im[2] : im[6];
  const float t5r = P ? re[3] : re[7], t5i = P ? im[3] : im[7];
  const float t6r = P ? re[1] : re[5], t6i = P ? im[1] : im[5];
  const float t7r = P ? re[0] : re[4], t7i = P ? im[0] : im[4];
  re[0] = bperm(addr_e, t0r); re[1] = bperm(addr_o, t1r);
  re[2] = bperm(addr_e, t2r); re[3] = bperm(addr_o, t3r);
  re[4] = bperm(addr_e, t4r); re[5] = bperm(addr_o, t5r);
  re[6] = bperm(addr_e, t6r); re[7] = bperm(addr_o, t7r);
  im[0] = bperm(addr_e, t0i); im[1] = bperm(addr_o, t1i);
  im[2] = bperm(addr_e, t2i); im[3] = bperm(addr_o, t3i);
  im[4] = bperm(addr_e, t4i); im[5] = bperm(addr_o, t5i);
  im[6] = bperm(addr_e, t6i); im[7] = bperm(addr_o, t7i);
}

__global__ __launch_bounds__(256, 2) void vqc_kernel(const float* __restrict__ x,
                                                     const float* __restrict__ w,
                                                     float* __restrict__ out) {
  const int lane = (int)(threadIdx.x & 63);
  const int wv = (int)((blockIdx.x * blockDim.x + threadIdx.x) >> 6);
  const int hl = lane & 31;

  // ring gather addresses: src lane = (lane&32) | gray5(hl); odd regs ^0x18
  const int ghl    = hl ^ (hl >> 1);                 // 5-bit gray
  const int addr_e = ((lane & 32) | ghl) << 2;
  const int addr_o = addr_e ^ 0x60;
  const bool Ppar  = (__popc(hl) & 1) != 0;

  // per-wire sign masks (wires 0..4 <-> lane bits 4..0)
  unsigned sm[5];
#pragma unroll
  for (int W = 0; W < 5; ++W)
    sm[W] = ((lane >> (4 - W)) & 1) ? 0u : 0x80000000u;

  // ---- ONE sincos: lanes 0..47 -> w[lane]; lanes 48..63 -> this wave's two
  // samples' x. Keep the half-angle (ha) for the rz_diag angle sums.
  float sn, cs, ha;
  {
    const float wvv = w[lane];
    const float xv  = x[(wv << 4) | (lane & 15)];
    ha = ((lane >= 48) ? xv : wvv) * 0.5f;
    __sincosf(ha, &sn, &cs);
  }
  float cy48, sy48;
  __sincosf(w[48] * 0.5f, &sy48, &cy48);

  // ---- distribute this HALF's encoding sincos values (per-sample)
  float fc[8], fs[8];
  {
    const int fbase = (48 + ((lane >> 5) << 3)) << 2;
#pragma unroll
    for (int k = 0; k < 8; ++k) {
      fc[k] = bperm(fbase + (k << 2), cs);
      fs[k] = bperm(fbase + (k << 2), sn);
    }
  }

  // ---- closed-form post-ring-0 REAL state
  float re[8], im[8];
  {
    const int HL4 = (lane >> 4) & 1, G3 = (ghl >> 3) & 1, HL0 = lane & 1;
    const float Pl = ((ghl & 4) ? fs[2] : fc[2]) *
                     ((ghl & 2) ? fs[3] : fc[3]) *
                     ((ghl & 1) ? fs[4] : fc[4]);
    const float q0 = (HL4 ? fs[0] : fc[0]) * (G3 ? fs[1] : fc[1]);
    const float q1 = (HL4 ? fc[0] : fs[0]) * (G3 ? fc[1] : fs[1]);
    const float g50 = HL0 ? fs[5] : fc[5];
    const float g51 = HL0 ? fc[5] : fs[5];
    const float a0 = Pl * q0 * g50, a1 = Pl * q1 * g50;
    const float b0 = Pl * q0 * g51, b1 = Pl * q1 * g51;
    const float cc = fc[6] * fc[7], csx = fc[6] * fs[7];
    const float sc = fs[6] * fc[7], ssx = fs[6] * fs[7];
    re[0] = a0 * cc;  re[1] = a1 * csx; re[2] = a0 * ssx; re[3] = a1 * sc;
    re[4] = b0 * sc;  re[5] = b1 * ssx; re[6] = b0 * csx; re[7] = b1 * cc;
  }

  // ---- layer 0 (ring folded): all 8 RYs on the REAL state, then the fused
  // RZ diagonal applied to a real state.
  ry_real<0>(re, rlane(cs, 0),  rlane(sn, 0),  sm[0]);
  ry_real<1>(re, rlane(cs, 2),  rlane(sn, 2),  sm[1]);
  ry_real<2>(re, rlane(cs, 4),  rlane(sn, 4),  sm[2]);
  ry_real<3>(re, rlane(cs, 6),  rlane(sn, 6),  sm[3]);
  ry_real<4>(re, rlane(cs, 8),  rlane(sn, 8),  sm[4]);
  ry_real<5>(re, rlane(cs, 10), rlane(sn, 10), 0u);
  ry_real<6>(re, rlane(cs, 12), rlane(sn, 12), 0u);
  ry_real<7>(re, rlane(cs, 14), rlane(sn, 14), 0u);
  rz_diag<true>(re, im, cs, sn, ha, sm, 0);

  // ---- layers 1..2: ring + all RYs + fused RZ diagonal
#pragma unroll
  for (int l = 1; l < NL - 1; ++l) {
    ring2(re, im, addr_e, addr_o, Ppar);
    const int base = l * 16;
    ry_gate<0>(re, im, rlane(cs, base + 0),  rlane(sn, base + 0),  sm[0]);
    ry_gate<1>(re, im, rlane(cs, base + 2),  rlane(sn, base + 2),  sm[1]);
    ry_gate<2>(re, im, rlane(cs, base + 4),  rlane(sn, base + 4),  sm[2]);
    ry_gate<3>(re, im, rlane(cs, base + 6),  rlane(sn, base + 6),  sm[3]);
    ry_gate<4>(re, im, rlane(cs, base + 8),  rlane(sn, base + 8),  sm[4]);
    ry_gate<5>(re, im, rlane(cs, base + 10), rlane(sn, base + 10), 0u);
    ry_gate<6>(re, im, rlane(cs, base + 12), rlane(sn, base + 12), 0u);
    ry_gate<7>(re, im, rlane(cs, base + 14), rlane(sn, base + 14), 0u);
    rz_diag<false>(re, im, cs, sn, ha, sm, base);
  }

  // ---- last layer folded: ring_3 + RY(w[48]) + <Z_0> in one pass.
  // Post-ring A7 flip <-> pre-ring hl bits {4,3} flip == lane^0x18, same reg.
  // A7 = parity(hl&0xF) ^ par3(reg); ss = A7 ? +s : -s; Z-sign = -A7.
  {
    const unsigned pm0 = (unsigned)(__popc(lane & 15) & 1) << 31;
    float acc = 0.f;
#pragma unroll
    for (int r = 0; r < 8; ++r) {
      const unsigned podd =
          ((r == 1) | (r == 2) | (r == 4) | (r == 7)) ? 0x80000000u : 0u;
      const unsigned pmr = pm0 ^ podd;
      const float ssy = sxor(sy48, pmr ^ 0x80000000u);
      const float pr = swz18(re[r]);
      const float pi = swz18(im[r]);
      const float nr = cy48 * re[r] + ssy * pr;
      const float ni = cy48 * im[r] + ssy * pi;
      acc += sxor(nr * nr + ni * ni, pmr);  // + when A7=0, - when A7=1
    }
    // reduce over the 32-lane half
    acc += dppx<0xB1>(acc);   // ^1
    acc += dppx<0x4E>(acc);   // ^2
    acc += swz4(acc);         // ^4
    acc += dppx<0x128>(acc);  // ^8
    acc += swz16(acc);        // ^16
    if ((lane & 31) == 0) out[(wv << 1) | (lane >> 5)] = acc;
  }
}

extern "C" void kernel_launch(void* const* d_in, const int* in_sizes, int n_in,
                              void* d_out, int out_size, void* d_ws, size_t ws_size,
                              hipStream_t stream) {
  const float* x = (const float*)d_in[0];   // (4096, 8) f32
  const float* w = (const float*)d_in[1];   // (4, 8, 2) f32
  float* out = (float*)d_out;               // (4096,) f32
  (void)in_sizes; (void)n_in; (void)out_size; (void)d_ws; (void)ws_size;

  // 2 samples per wave: 2048 waves = 512 blocks x 256 threads = 2 waves/SIMD
  dim3 grid(BATCH / 2 * 64 / 256), block(256);
  hipLaunchKernelGGL(vqc_kernel, grid, block, 0, stream, x, w, out);
}

// Round 6
// 58.493 us; speedup vs baseline: 1.1251x; 1.0276x over previous
//
#include <hip/hip_runtime.h>

#define NQ 8
#define NL 4
#define BATCH 4096

// ---------------------------------------------------------------------------
// Layout: one wave = TWO samples. Sample = lane bit 5. Per sample:
// 256 amps = 32 lanes x 8 regs; amp bits A7..A3 = hl bits 4..0 (hl=lane&31),
// A2..A0 = reg bits 2..0. Wire i <-> A_{7-i}: wires 0-4 cross-lane
// (xor 16,8,4,2,1), wires 5-7 in-register (reg xor 4,2,1).
//
// r6 NEW — packed-f32 state (VOP3P v_pk_mul_f32 / v_pk_fma_f32):
// state stored as float2 {re, im}. In RY and the fused RZ diagonal, re and
// im undergo the SAME linear combination with the same wave-uniform
// coefficients -> one packed op does both components. Halves the ~700
// scalar mul/fma in the gate path (~1450 -> ~1050 instr/wave). Cross-lane
// exchanges remain 2x32-bit DS/DPP ops (no packed variant exists).
//
// Carried from r2-r5 (all exact):
//  * CNOT ring = one wave-wide gray-code permutation gather.
//  * Encoding + ring0 folded to closed-form REAL product state.
//  * RZ-layer fusion: layer == [RY(0..7)] then ONE diagonal; phase split
//    into per-lane angle sum (1 sincos/layer) + 8 wave-uniform reg combos.
//  * Layer 0 all-real RYs (half cost) + real-input diagonal.
//  * Last ring + RY(w[48]) + <Z_0> folded into readout (partner lane^0x18,
//    sign = parity(lane&15)^par3(reg)).
//  * One lane-parallel sincos for all 48 weight + 16 x angles.
// ---------------------------------------------------------------------------

typedef float v2f __attribute__((ext_vector_type(2)));

template <int CTRL>
__device__ __forceinline__ float dppx(float v) {
  return __int_as_float(
      __builtin_amdgcn_update_dpp(0, __float_as_int(v), CTRL, 0xF, 0xF, true));
}

__device__ __forceinline__ float swz16(float v) {  // lane ^ 16
  return __int_as_float(__builtin_amdgcn_ds_swizzle(__float_as_int(v), 0x401F));
}
__device__ __forceinline__ float swz4(float v) {   // lane ^ 4
  return __int_as_float(__builtin_amdgcn_ds_swizzle(__float_as_int(v), 0x101F));
}
__device__ __forceinline__ float swz18(float v) {  // lane ^ 0x18
  return __int_as_float(__builtin_amdgcn_ds_swizzle(__float_as_int(v), 0x601F));
}
__device__ __forceinline__ float bperm(int addr, float v) {  // full-wave pull
  return __int_as_float(__builtin_amdgcn_ds_bpermute(addr, __float_as_int(v)));
}
__device__ __forceinline__ float rlane(float v, int l) {     // lane -> SGPR
  return __int_as_float(__builtin_amdgcn_readlane(__float_as_int(v), l));
}
__device__ __forceinline__ float sxor(float v, unsigned m) { // sign via xor
  return __int_as_float(__float_as_int(v) ^ m);
}
__device__ __forceinline__ v2f pfma(v2f a, v2f b, v2f c) {   // v_pk_fma_f32
  return __builtin_elementwise_fma(a, b, c);
}

// lane exchange along wire W (0..4): partner differs in lane bit (4-W)
template <int W>
__device__ __forceinline__ float xl(float v) {
  if constexpr (W == 0) return swz16(v);             // lane ^ 16
  else if constexpr (W == 1) return dppx<0x128>(v);  // row_ror:8 == lane ^ 8
  else if constexpr (W == 2) return swz4(v);         // lane ^ 4
  else if constexpr (W == 3) return dppx<0x4E>(v);   // quad_perm [2,3,0,1] ^2
  else return dppx<0xB1>(v);                         // quad_perm [1,0,3,2] ^1
}

// m: 0 where wire-bit==1 (ss=+s), 0x80000000 where wire-bit==0 (ss=-s)
template <int W>
__device__ __forceinline__ void ry_gate(v2f a[8], float c, float s, unsigned m) {
  if constexpr (W <= 4) {
    const float ss = sxor(s, m);
    const v2f cv = {c, c}, sv = {ss, ss};
#pragma unroll
    for (int r = 0; r < 8; ++r) {
      v2f p = {xl<W>(a[r].x), xl<W>(a[r].y)};
      a[r] = pfma(p, sv, a[r] * cv);
    }
  } else {
    constexpr int mm = 1 << (7 - W);
    const v2f cv = {c, c}, sv = {s, s}, msv = {-s, -s};
#pragma unroll
    for (int r = 0; r < 8; ++r) {
      if ((r & mm) == 0) {
        const int r1 = r | mm;
        const v2f a0 = a[r], a1 = a[r1];
        a[r]  = pfma(a1, msv, a0 * cv);
        a[r1] = pfma(a0, sv,  a1 * cv);
      }
    }
  }
}

// real-state RY (layer 0): acts on scalar re[] only
template <int W>
__device__ __forceinline__ void ry_real(float re[8], float c, float s,
                                        unsigned m) {
  if constexpr (W <= 4) {
    const float ss = sxor(s, m);
#pragma unroll
    for (int r = 0; r < 8; ++r) {
      float pr = xl<W>(re[r]);
      re[r] = c * re[r] + ss * pr;
    }
  } else {
    constexpr int mm = 1 << (7 - W);
#pragma unroll
    for (int r = 0; r < 8; ++r) {
      if ((r & mm) == 0) {
        const int r1 = r | mm;
        float a0 = re[r], a1 = re[r1];
        re[r]  = c * a0 - s * a1;
        re[r1] = s * a0 + c * a1;
      }
    }
  }
}

// Fused RZ diagonal for one layer: amp *= exp(i*phi), phi = sum_i ±theta_i/2
// (+ where wire-bit==1). Wires 0-4 -> per-lane angle sum + one sincos;
// wires 5-7 -> 8 wave-uniform (cR,sR) with conj symmetry r <-> 7-r.
template <bool REAL>
__device__ __forceinline__ void rz_diag(const float reIn[8], v2f a[8],
                                        float cs, float sn, float ha,
                                        const unsigned* sm, int base) {
  float phL = sxor(rlane(ha, base + 1), sm[0]);
  phL += sxor(rlane(ha, base + 3), sm[1]);
  phL += sxor(rlane(ha, base + 5), sm[2]);
  phL += sxor(rlane(ha, base + 7), sm[3]);
  phL += sxor(rlane(ha, base + 9), sm[4]);
  float sL, cL;
  __sincosf(phL, &sL, &cL);
  const float c5 = rlane(cs, base + 11), s5 = rlane(sn, base + 11);
  const float c6 = rlane(cs, base + 13), s6 = rlane(sn, base + 13);
  const float c7 = rlane(cs, base + 15), s7 = rlane(sn, base + 15);
  const float m1 = c5 * c6, m2 = s5 * s6, m3 = s5 * c6, m4 = c5 * s6;
  const float ppr = m1 - m2, ppi = m3 + m4;   // ph5+ * ph6+
  const float pmr = m1 + m2, pmi = m3 - m4;   // ph5+ * ph6-
  float cR[4], sR[4];                          // index k = r-4 for r=4..7
  {
    const float aa = pmr * c7, bb = pmi * s7, c2 = pmi * c7, dd = pmr * s7;
    cR[0] = aa + bb; sR[0] = c2 - dd;   // r=4
    cR[1] = aa - bb; sR[1] = c2 + dd;   // r=5
  }
  {
    const float aa = ppr * c7, bb = ppi * s7, c2 = ppi * c7, dd = ppr * s7;
    cR[2] = aa + bb; sR[2] = c2 - dd;   // r=6
    cR[3] = aa - bb; sR[3] = c2 + dd;   // r=7
  }
#pragma unroll
  for (int r = 0; r < 8; ++r) {
    const int k = (r < 4) ? (3 - r) : (r - 4);          // conj pair r ^ 7
    const float cRr = cR[k];
    const float sRr = (r < 4) ? -sR[k] : sR[k];
    const float C = cL * cRr - sL * sRr;
    const float S = sL * cRr + cL * sRr;
    if constexpr (REAL) {
      const float t = reIn[r];
      a[r] = (v2f){C * t, S * t};
    } else {
      const v2f sw = a[r].yx;
      const v2f C2 = {C, C}, S2 = {-S, S};
      a[r] = pfma(sw, S2, a[r] * C2);   // {C*re - S*im, C*im + S*re}
    }
  }
}

// Entire CNOT ring as one permutation gather (both samples at once).
__device__ __forceinline__ void ring2(v2f a[8], int addr_e, int addr_o, bool P) {
  const v2f t0 = P ? a[4] : a[0];
  const v2f t1 = P ? a[5] : a[1];
  const v2f t2 = P ? a[7] : a[3];
  const v2f t3 = P ? a[6] : a[2];
  const v2f t4 = P ? a[2] : a[6];
  const v2f t5 = P ? a[3] : a[7];
  const v2f t6 = P ? a[1] : a[5];
  const v2f t7 = P ? a[0] : a[4];
  a[0] = (v2f){bperm(addr_e, t0.x), bperm(addr_e, t0.y)};
  a[1] = (v2f){bperm(addr_o, t1.x), bperm(addr_o, t1.y)};
  a[2] = (v2f){bperm(addr_e, t2.x), bperm(addr_e, t2.y)};
  a[3] = (v2f){bperm(addr_o, t3.x), bperm(addr_o, t3.y)};
  a[4] = (v2f){bperm(addr_e, t4.x), bperm(addr_e, t4.y)};
  a[5] = (v2f){bperm(addr_o, t5.x), bperm(addr_o, t5.y)};
  a[6] = (v2f){bperm(addr_e, t6.x), bperm(addr_e, t6.y)};
  a[7] = (v2f){bperm(addr_o, t7.x), bperm(addr_o, t7.y)};
}

__global__ __launch_bounds__(256, 2) void vqc_kernel(const float* __restrict__ x,
                                                     const float* __restrict__ w,
                                                     float* __restrict__ out) {
  const int lane = (int)(threadIdx.x & 63);
  const int wv = (int)((blockIdx.x * blockDim.x + threadIdx.x) >> 6);
  const int hl = lane & 31;

  // ring gather addresses: src lane = (lane&32) | gray5(hl); odd regs ^0x18
  const int ghl    = hl ^ (hl >> 1);                 // 5-bit gray
  const int addr_e = ((lane & 32) | ghl) << 2;
  const int addr_o = addr_e ^ 0x60;
  const bool Ppar  = (__popc(hl) & 1) != 0;

  // per-wire sign masks (wires 0..4 <-> lane bits 4..0)
  unsigned sm[5];
#pragma unroll
  for (int W = 0; W < 5; ++W)
    sm[W] = ((lane >> (4 - W)) & 1) ? 0u : 0x80000000u;

  // ---- ONE sincos: lanes 0..47 -> w[lane]; lanes 48..63 -> this wave's two
  // samples' x. Keep the half-angle (ha) for the rz_diag angle sums.
  float sn, cs, ha;
  {
    const float wvv = w[lane];
    const float xv  = x[(wv << 4) | (lane & 15)];
    ha = ((lane >= 48) ? xv : wvv) * 0.5f;
    __sincosf(ha, &sn, &cs);
  }
  float cy48, sy48;
  __sincosf(w[48] * 0.5f, &sy48, &cy48);

  // ---- distribute this HALF's encoding sincos values (per-sample)
  float fc[8], fs[8];
  {
    const int fbase = (48 + ((lane >> 5) << 3)) << 2;
#pragma unroll
    for (int k = 0; k < 8; ++k) {
      fc[k] = bperm(fbase + (k << 2), cs);
      fs[k] = bperm(fbase + (k << 2), sn);
    }
  }

  // ---- closed-form post-ring-0 REAL state
  float re[8];
  {
    const int HL4 = (lane >> 4) & 1, G3 = (ghl >> 3) & 1, HL0 = lane & 1;
    const float Pl = ((ghl & 4) ? fs[2] : fc[2]) *
                     ((ghl & 2) ? fs[3] : fc[3]) *
                     ((ghl & 1) ? fs[4] : fc[4]);
    const float q0 = (HL4 ? fs[0] : fc[0]) * (G3 ? fs[1] : fc[1]);
    const float q1 = (HL4 ? fc[0] : fs[0]) * (G3 ? fc[1] : fs[1]);
    const float g50 = HL0 ? fs[5] : fc[5];
    const float g51 = HL0 ? fc[5] : fs[5];
    const float a0 = Pl * q0 * g50, a1 = Pl * q1 * g50;
    const float b0 = Pl * q0 * g51, b1 = Pl * q1 * g51;
    const float cc = fc[6] * fc[7], csx = fc[6] * fs[7];
    const float sc = fs[6] * fc[7], ssx = fs[6] * fs[7];
    re[0] = a0 * cc;  re[1] = a1 * csx; re[2] = a0 * ssx; re[3] = a1 * sc;
    re[4] = b0 * sc;  re[5] = b1 * ssx; re[6] = b0 * csx; re[7] = b1 * cc;
  }

  // ---- layer 0 (ring folded): all 8 RYs on the REAL state, then the fused
  // RZ diagonal applied to the real state (packs into v2f a[8]).
  v2f a[8];
  ry_real<0>(re, rlane(cs, 0),  rlane(sn, 0),  sm[0]);
  ry_real<1>(re, rlane(cs, 2),  rlane(sn, 2),  sm[1]);
  ry_real<2>(re, rlane(cs, 4),  rlane(sn, 4),  sm[2]);
  ry_real<3>(re, rlane(cs, 6),  rlane(sn, 6),  sm[3]);
  ry_real<4>(re, rlane(cs, 8),  rlane(sn, 8),  sm[4]);
  ry_real<5>(re, rlane(cs, 10), rlane(sn, 10), 0u);
  ry_real<6>(re, rlane(cs, 12), rlane(sn, 12), 0u);
  ry_real<7>(re, rlane(cs, 14), rlane(sn, 14), 0u);
  rz_diag<true>(re, a, cs, sn, ha, sm, 0);

  // ---- layers 1..2: ring + all RYs (packed) + fused RZ diagonal (packed)
#pragma unroll
  for (int l = 1; l < NL - 1; ++l) {
    ring2(a, addr_e, addr_o, Ppar);
    const int base = l * 16;
    ry_gate<0>(a, rlane(cs, base + 0),  rlane(sn, base + 0),  sm[0]);
    ry_gate<1>(a, rlane(cs, base + 2),  rlane(sn, base + 2),  sm[1]);
    ry_gate<2>(a, rlane(cs, base + 4),  rlane(sn, base + 4),  sm[2]);
    ry_gate<3>(a, rlane(cs, base + 6),  rlane(sn, base + 6),  sm[3]);
    ry_gate<4>(a, rlane(cs, base + 8),  rlane(sn, base + 8),  sm[4]);
    ry_gate<5>(a, rlane(cs, base + 10), rlane(sn, base + 10), 0u);
    ry_gate<6>(a, rlane(cs, base + 12), rlane(sn, base + 12), 0u);
    ry_gate<7>(a, rlane(cs, base + 14), rlane(sn, base + 14), 0u);
    rz_diag<false>(re, a, cs, sn, ha, sm, base);
  }

  // ---- last layer folded: ring_3 + RY(w[48]) + <Z_0> in one pass.
  // Post-ring A7 flip <-> pre-ring hl bits {4,3} flip == lane^0x18, same reg.
  // A7 = parity(hl&0xF) ^ par3(reg); ss = A7 ? +s : -s; Z-sign = -A7.
  {
    const unsigned pm0 = (unsigned)(__popc(lane & 15) & 1) << 31;
    const v2f cv = {cy48, cy48};
    float acc = 0.f;
#pragma unroll
    for (int r = 0; r < 8; ++r) {
      const unsigned podd =
          ((r == 1) | (r == 2) | (r == 4) | (r == 7)) ? 0x80000000u : 0u;
      const unsigned pmr = pm0 ^ podd;
      const float ssy = sxor(sy48, pmr ^ 0x80000000u);
      const v2f sv = {ssy, ssy};
      const v2f p = {swz18(a[r].x), swz18(a[r].y)};
      const v2f n = pfma(p, sv, a[r] * cv);
      const v2f nn = n * n;
      acc += sxor(nn.x + nn.y, pmr);  // + when A7=0, - when A7=1
    }
    // reduce over the 32-lane half
    acc += dppx<0xB1>(acc);   // ^1
    acc += dppx<0x4E>(acc);   // ^2
    acc += swz4(acc);         // ^4
    acc += dppx<0x128>(acc);  // ^8
    acc += swz16(acc);        // ^16
    if ((lane & 31) == 0) out[(wv << 1) | (lane >> 5)] = acc;
  }
}

extern "C" void kernel_launch(void* const* d_in, const int* in_sizes, int n_in,
                              void* d_out, int out_size, void* d_ws, size_t ws_size,
                              hipStream_t stream) {
  const float* x = (const float*)d_in[0];   // (4096, 8) f32
  const float* w = (const float*)d_in[1];   // (4, 8, 2) f32
  float* out = (float*)d_out;               // (4096,) f32
  (void)in_sizes; (void)n_in; (void)out_size; (void)d_ws; (void)ws_size;

  // 2 samples per wave: 2048 waves = 512 blocks x 256 threads = 2 waves/SIMD
  dim3 grid(BATCH / 2 * 64 / 256), block(256);
  hipLaunchKernelGGL(vqc_kernel, grid, block, 0, stream, x, w, out);
}